// Round 11
// baseline (327.284 us; speedup 1.0000x reference)
//
#include <hip/hip_runtime.h>

// ---------------- problem constants ----------------
#define NUM_GRAPHS 64
#define NODE_SZ    200
#define FEAT       200
#define HID        256
#define HALF       128
#define N_NODES    (NUM_GRAPHS * NODE_SZ)   // 12800
#define KREAD      (NODE_SZ * HID)          // 51200
#define KSTRIDE    512                      // padded K for conv inputs/weights
#define HBLK       128                      // histogram/scatter blocks

typedef unsigned short ushort_t;
typedef unsigned int uint_t;
typedef __attribute__((ext_vector_type(8))) short bf16x8;
typedef __attribute__((ext_vector_type(4))) float f32x4;

#define GAS(p) ((const __attribute__((address_space(1))) void*)(p))
#define LAS(p) ((__attribute__((address_space(3))) void*)(p))

__device__ __forceinline__ float bf2f(ushort_t u) {
    union { unsigned int i; float f; } v; v.i = ((unsigned int)u) << 16; return v.f;
}
__device__ __forceinline__ ushort_t f2bf(float f) {
    union { float f; unsigned int i; } v; v.f = f;
    unsigned int x = v.i;
    unsigned int r = (x + 0x7fffu + ((x >> 16) & 1u)) >> 16;  // RNE
    return (ushort_t)r;
}

// ---------------- CSR build (no global atomics) ----------------
__global__ __launch_bounds__(1024) void bhist_kernel(const int* __restrict__ ei,
                                                     const float* __restrict__ ew,
                                                     uint_t* __restrict__ bh, int E) {
    __shared__ uint_t h[N_NODES];
    for (int i = threadIdx.x; i < N_NODES; i += 1024) h[i] = 0;
    __syncthreads();
    int b = blockIdx.x;
    int epb = (E + HBLK - 1) / HBLK;
    int e0 = b * epb, e1 = min(e0 + epb, E);
    for (int e = e0 + threadIdx.x; e < e1; e += 1024) {
        int dst = ei[E + e];
        float w = ew[e];
        if (w > 0.0f)      atomicAdd(&h[dst], 1u);
        else if (w < 0.0f) atomicAdd(&h[dst], 0x10000u);
    }
    __syncthreads();
    uint_t* out = bh + (size_t)b * N_NODES;
    for (int i = threadIdx.x * 4; i < N_NODES; i += 4096)
        *(uint4*)&out[i] = *(const uint4*)&h[i];
}

// Column prefix over the block-histograms; ILP-8 batched loads to hide latency
// (only 200 waves chip-wide — serial version was latency-exposed).
__global__ void colpref_kernel(uint_t* __restrict__ bh, int* __restrict__ counts,
                               int* __restrict__ cnt_p) {
    int n = blockIdx.x * 256 + threadIdx.x;
    if (n >= N_NODES) return;
    uint_t seq = 0;
#pragma unroll 1
    for (int b = 0; b < HBLK; b += 8) {
        uint_t v[8];
#pragma unroll
        for (int j = 0; j < 8; ++j) v[j] = bh[(size_t)(b + j) * N_NODES + n];
#pragma unroll
        for (int j = 0; j < 8; ++j) {
            bh[(size_t)(b + j) * N_NODES + n] = seq;
            seq += v[j];
        }
    }
    counts[n] = (int)((seq & 0xffffu) + (seq >> 16));
    cnt_p[n]  = (int)(seq & 0xffffu);
}

__global__ __launch_bounds__(1024) void scan_kernel(const int* __restrict__ counts,
                                                    const int* __restrict__ cnt_p,
                                                    uint2* __restrict__ obnd, int n) {
    const int PER = 13;
    int t = threadIdx.x;
    int start = t * PER;
    int local[PER];
    int sum = 0;
#pragma unroll
    for (int i = 0; i < PER; ++i) {
        int idx = start + i;
        int v = (idx < n) ? counts[idx] : 0;
        local[i] = sum;
        sum += v;
    }
    int lane = t & 63, wid = t >> 6;
    int inc = sum;
#pragma unroll
    for (int d = 1; d < 64; d <<= 1) {
        int up = __shfl_up(inc, d);
        if (lane >= d) inc += up;
    }
    __shared__ int wsum[16], woff[16];
    if (lane == 63) wsum[wid] = inc;
    __syncthreads();
    if (t < 16) {
        int acc = 0;
        for (int j = 0; j < 16; ++j) if (j < t) acc += wsum[j];
        woff[t] = acc;
    }
    __syncthreads();
    int base = woff[wid] + (inc - sum);
#pragma unroll
    for (int i = 0; i < PER; ++i) {
        int idx = start + i;
        if (idx < n) {
            uint_t off = (uint_t)(base + local[i]);
            obnd[idx] = make_uint2(off, off + (uint_t)cnt_p[idx]);
        }
    }
    if (t == 1023) {
        uint_t tot = (uint_t)(base + sum);
        obnd[n] = make_uint2(tot, tot);
    }
}

// ---------------- scatter + all casts, one launch ----------------
// blocks [0,128): scatter; [128,512): weight castpad; [512,1137): x cast.
__global__ __launch_bounds__(1024) void scat_prep_kernel(
        const int* __restrict__ ei, const float* __restrict__ ew,
        const uint_t* __restrict__ bh, const uint2* __restrict__ obnd,
        uint2* __restrict__ es, int E,
        const float* __restrict__ W0p, const float* __restrict__ W0n,
        const float* __restrict__ W1p, const float* __restrict__ W1n,
        const float* __restrict__ W2p, const float* __restrict__ W2n,
        const float* __restrict__ x,
        ushort_t* __restrict__ wcast, ushort_t* __restrict__ xb) {
    __shared__ uint_t cur[N_NODES];
    int bx = blockIdx.x;
    if (bx < HBLK) {
        const uint_t* pref = bh + (size_t)bx * N_NODES;
        for (int i = threadIdx.x * 4; i < N_NODES; i += 4096)
            *(uint4*)&cur[i] = *(const uint4*)&pref[i];
        __syncthreads();
        int epb = (E + HBLK - 1) / HBLK;
        int e0 = bx * epb, e1 = min(e0 + epb, E);
        for (int e = e0 + threadIdx.x; e < e1; e += 1024) {
            int src = ei[e];
            int dst = ei[E + e];
            float w = ew[e];
            if (w > 0.0f) {
                uint_t old = atomicAdd(&cur[dst], 1u);
                uint_t pos = obnd[dst].x + (old & 0xffffu);
                es[pos] = make_uint2((uint_t)src, __float_as_uint(w));
            } else if (w < 0.0f) {
                uint_t old = atomicAdd(&cur[dst], 0x10000u);
                uint_t pos = obnd[dst].y + (old >> 16);
                es[pos] = make_uint2((uint_t)src, __float_as_uint(-w));
            }
        }
    } else if (bx < 512) {
        int idx = (bx - 128) * 1024 + threadIdx.x;      // < 6*65536
        int task = idx >> 16;
        int within = idx & 65535;
        const float* W = (task == 0) ? W0p : (task == 1) ? W0n : (task == 2) ? W1p
                       : (task == 3) ? W1n : (task == 4) ? W2p : W2n;
        int K2 = (task < 2) ? 400 : 512;
        int row = within >> 9;
        int col = within & (KSTRIDE - 1);
        wcast[task * 65536 + within] = (col < K2) ? f2bf(W[(size_t)row * K2 + col]) : (ushort_t)0;
    } else {
        int i = ((bx - 512) * 1024 + threadIdx.x) * 4;
        if (i < N_NODES * FEAT) {
            float4 v = *(const float4*)&x[i];
            ushort4 o;
            o.x = f2bf(v.x); o.y = f2bf(v.y); o.z = f2bf(v.z); o.w = f2bf(v.w);
            *(ushort4*)&xb[i] = o;
        }
    }
}

// ---------------- signed aggregation: 4 waves/block, one node per wave ----------------
// Half-wave 0 (lanes 0-31) takes even edges, half-wave 1 odd edges; each lane owns
// 8 cols (one uint4 = 16 B load). 2 edges + 1 KB per load instruction; halves
// combined by shfl at the end (fp32 reassociation only).
template <int D>
__global__ __launch_bounds__(256) void agg_kernel(
        const ushort_t* __restrict__ hb,
        const uint2* __restrict__ obnd,
        const uint2* __restrict__ es,
        ushort_t* __restrict__ Ap, ushort_t* __restrict__ An) {
    constexpr int ACT = D / 8;            // active lanes per half: 32 (D=256) / 25 (D=200)
    int lane = threadIdx.x & 63;
    int wv   = threadIdx.x >> 6;
    int half = lane >> 5;
    int hl   = lane & 31;
    int n = blockIdx.x * 4 + wv;
    int c0 = min(hl, ACT - 1) * 8;
    uint2 ob = obnd[n];
    uint_t off = ob.x, mid = ob.y, end = obnd[n + 1].x;

    float ap[8] = {}, an[8] = {};

#pragma unroll 1
    for (int phase = 0; phase < 2; ++phase) {
        uint_t lo = phase ? mid : off;
        uint_t hi = phase ? end : mid;
        float* acc = phase ? an : ap;
#pragma unroll 1
        for (uint_t base = lo; base < hi; base += 64) {
            int cnt = (int)min(64u, hi - base);
            uint2 rec = es[base + (uint_t)min(lane, cnt - 1)];
            int i = 0;
#pragma unroll 1
            for (; i + 16 <= cnt; i += 16) {       // 16 edges, 8 x 16B loads per lane
                uint4 p[8]; float w[8];
#pragma unroll
                for (int j = 0; j < 8; ++j) {
                    int e = i + 2 * j + half;
                    int s = __shfl((int)rec.x, e);
                    w[j] = __uint_as_float((uint_t)__shfl((int)rec.y, e));
                    p[j] = *(const uint4*)&hb[(size_t)s * D + c0];
                }
#pragma unroll
                for (int j = 0; j < 8; ++j) {
                    const ushort_t* q = (const ushort_t*)&p[j];
#pragma unroll
                    for (int c = 0; c < 8; ++c) acc[c] = fmaf(w[j], bf2f(q[c]), acc[c]);
                }
            }
#pragma unroll 1
            for (; i + 2 <= cnt; i += 2) {         // 2 edges, 1 load per lane
                int e = i + half;
                int s = __shfl((int)rec.x, e);
                float w = __uint_as_float((uint_t)__shfl((int)rec.y, e));
                uint4 pk = *(const uint4*)&hb[(size_t)s * D + c0];
                const ushort_t* q = (const ushort_t*)&pk;
#pragma unroll
                for (int c = 0; c < 8; ++c) acc[c] = fmaf(w, bf2f(q[c]), acc[c]);
            }
            if (i < cnt) {                          // odd tail: half 0 only
                int s = __shfl((int)rec.x, i);
                float w = __uint_as_float((uint_t)__shfl((int)rec.y, i));
                if (half == 0) {
                    uint4 pk = *(const uint4*)&hb[(size_t)s * D + c0];
                    const ushort_t* q = (const ushort_t*)&pk;
#pragma unroll
                    for (int c = 0; c < 8; ++c) acc[c] = fmaf(w, bf2f(q[c]), acc[c]);
                }
            }
        }
    }

    // fold half 1 into half 0
#pragma unroll
    for (int c = 0; c < 8; ++c) {
        ap[c] += __shfl(ap[c], hl + 32);
        an[c] += __shfl(an[c], hl + 32);
    }

    size_t rb = (size_t)n * KSTRIDE;
    if (half == 0 && hl < ACT) {
        float dp = fmaxf((float)(mid - off), 1.0f);
        float dn = fmaxf((float)(end - mid), 1.0f);
        uint4 self = *(const uint4*)&hb[(size_t)n * D + c0];
        ushort_t op[8], on[8];
#pragma unroll
        for (int c = 0; c < 8; ++c) {
            op[c] = f2bf(ap[c] / dp);
            on[c] = f2bf(an[c] / dn);
        }
        *(uint4*)&Ap[rb + c0] = *(const uint4*)op;
        *(uint4*)&An[rb + c0] = *(const uint4*)on;
        *(uint4*)&Ap[rb + D + c0] = self;
        *(uint4*)&An[rb + D + c0] = self;
    }
    if (D == 200 && half == 0 && hl >= 25 && hl < 27) {   // zero pad cols 400..415
        uint4 z = {0, 0, 0, 0};
        *(uint4*)&Ap[rb + 400 + (hl - 25) * 8] = z;
        *(uint4*)&An[rb + 400 + (hl - 25) * 8] = z;
    }
}

// ---------------- conv linear via MFMA, async LDS staging + double buffer ----------------
template <int KSTEPS, bool LEAKY>
__global__ __launch_bounds__(256) void conv_mfma(
        const ushort_t* __restrict__ Ap, const ushort_t* __restrict__ An,
        const ushort_t* __restrict__ Wpb, const ushort_t* __restrict__ Wnb,
        const float* __restrict__ bp, const float* __restrict__ bn,
        ushort_t* __restrict__ hout) {
    __shared__ __align__(16) ushort_t As[2][64 * 32];    // 2 x 4 KB
    __shared__ __align__(16) ushort_t Bs[2][128 * 32];   // 2 x 8 KB
    int mBase = blockIdx.x * 64;
    bool neg = (blockIdx.y != 0);
    const ushort_t* A    = neg ? An : Ap;
    const ushort_t* W    = neg ? Wnb : Wpb;
    const float*    bias = neg ? bn : bp;
    int tid  = threadIdx.x;
    int lane = tid & 63;
    int wv   = tid >> 6;
    int r    = lane & 15;
    int quad = lane >> 4;

    int rowA = tid >> 2, colA = (tid & 3) * 8;
    const ushort_t* gA  = A + (size_t)(mBase + rowA) * KSTRIDE + colA;
    const ushort_t* gB0 = W + (size_t)rowA * KSTRIDE + colA;
    const ushort_t* gB1 = W + (size_t)(rowA + 64) * KSTRIDE + colA;

    f32x4 acc[8];
#pragma unroll
    for (int j = 0; j < 8; ++j) acc[j] = (f32x4){0.f, 0.f, 0.f, 0.f};

    __builtin_amdgcn_global_load_lds(GAS(gA),  LAS(&As[0][wv * 512]), 16, 0, 0);
    __builtin_amdgcn_global_load_lds(GAS(gB0), LAS(&Bs[0][wv * 512]), 16, 0, 0);
    __builtin_amdgcn_global_load_lds(GAS(gB1), LAS(&Bs[0][2048 + wv * 512]), 16, 0, 0);

    for (int kt = 0; kt < KSTEPS; ++kt) {
        int cur = kt & 1;
        __syncthreads();
        if (kt + 1 < KSTEPS) {
            int kB = (kt + 1) * 32;
            __builtin_amdgcn_global_load_lds(GAS(gA + kB),  LAS(&As[cur ^ 1][wv * 512]), 16, 0, 0);
            __builtin_amdgcn_global_load_lds(GAS(gB0 + kB), LAS(&Bs[cur ^ 1][wv * 512]), 16, 0, 0);
            __builtin_amdgcn_global_load_lds(GAS(gB1 + kB), LAS(&Bs[cur ^ 1][2048 + wv * 512]), 16, 0, 0);
        }
        bf16x8 a = *(const bf16x8*)&As[cur][(wv * 16 + r) * 32 + quad * 8];
#pragma unroll
        for (int j = 0; j < 8; ++j) {
            bf16x8 b = *(const bf16x8*)&Bs[cur][(j * 16 + r) * 32 + quad * 8];
            acc[j] = __builtin_amdgcn_mfma_f32_16x16x32_bf16(a, b, acc[j], 0, 0, 0);
        }
    }
    int colOff = neg ? HALF : 0;
#pragma unroll
    for (int j = 0; j < 8; ++j) {
        int c = j * 16 + r;
        float bv = bias[c];
#pragma unroll
        for (int reg = 0; reg < 4; ++reg) {
            int m = mBase + wv * 16 + quad * 4 + reg;
            float v = acc[j][reg] + bv;
            if (LEAKY) v = (v > 0.0f) ? v : 0.01f * v;
            hout[(size_t)m * HID + colOff + c] = f2bf(v);
        }
    }
}

// ---------------- readout via MFMA, split-K partials (no atomics) ----------------
__global__ __launch_bounds__(256) void readout_mfma(
        const ushort_t* __restrict__ h, const float* __restrict__ Wr,
        float* __restrict__ partial) {
    __shared__ __align__(16) ushort_t As[64 * 32];
    __shared__ __align__(16) ushort_t Bs[64 * 32];
    int nBase  = blockIdx.x * 64;
    int kStart = blockIdx.y * 800;
    int tid  = threadIdx.x;
    int lane = tid & 63;
    int wv   = tid >> 6;
    int r    = lane & 15;
    int quad = lane >> 4;

    f32x4 acc[4];
#pragma unroll
    for (int j = 0; j < 4; ++j) acc[j] = (f32x4){0.f, 0.f, 0.f, 0.f};

    for (int kt = 0; kt < 25; ++kt) {
        int kBase = kStart + kt * 32;
        int lin = tid * 8;
        int row = lin >> 5, col = lin & 31;
        *(uint4*)&As[lin] = *(const uint4*)&h[(size_t)row * KREAD + kBase + col];
        {
            const float* wp = &Wr[(size_t)(nBase + row) * KREAD + kBase + col];
            float4 f0 = *(const float4*)&wp[0];
            float4 f1 = *(const float4*)&wp[4];
            ushort4 b0, b1;
            b0.x = f2bf(f0.x); b0.y = f2bf(f0.y); b0.z = f2bf(f0.z); b0.w = f2bf(f0.w);
            b1.x = f2bf(f1.x); b1.y = f2bf(f1.y); b1.z = f2bf(f1.z); b1.w = f2bf(f1.w);
            *(ushort4*)&Bs[lin]     = b0;
            *(ushort4*)&Bs[lin + 4] = b1;
        }
        __syncthreads();
        bf16x8 a = *(const bf16x8*)&As[(wv * 16 + r) * 32 + quad * 8];
#pragma unroll
        for (int j = 0; j < 4; ++j) {
            bf16x8 b = *(const bf16x8*)&Bs[(j * 16 + r) * 32 + quad * 8];
            acc[j] = __builtin_amdgcn_mfma_f32_16x16x32_bf16(a, b, acc[j], 0, 0, 0);
        }
        __syncthreads();
    }
    float* out = partial + (size_t)blockIdx.y * (64 * HID);
#pragma unroll
    for (int j = 0; j < 4; ++j) {
        int c = nBase + j * 16 + r;
#pragma unroll
        for (int reg = 0; reg < 4; ++reg) {
            int g = wv * 16 + quad * 4 + reg;
            out[g * HID + c] = acc[j][reg];
        }
    }
}

// ---------------- final: fold 64 partials, dot with Wl ----------------
__global__ void final_kernel(const float* __restrict__ partial, const float* __restrict__ br,
                             const float* __restrict__ Wl, const float* __restrict__ bl,
                             float* __restrict__ out) {
    int g = blockIdx.x;
    int c = threadIdx.x;   // 256
    float s = 0.0f;
#pragma unroll 4
    for (int k = 0; k < 64; ++k) s += partial[(size_t)k * (64 * HID) + g * HID + c];
    float v = (s + br[c]) * Wl[c];
#pragma unroll
    for (int d = 32; d > 0; d >>= 1) v += __shfl_down(v, d);
    __shared__ float sh[4];
    if ((c & 63) == 0) sh[c >> 6] = v;
    __syncthreads();
    if (c == 0) out[g] = sh[0] + sh[1] + sh[2] + sh[3] + bl[0];
}

// ---------------- launch ----------------
extern "C" void kernel_launch(void* const* d_in, const int* in_sizes, int n_in,
                              void* d_out, int out_size, void* d_ws, size_t ws_size,
                              hipStream_t stream) {
    const float* x  = (const float*)d_in[0];
    const int*   ei = (const int*)d_in[1];
    const float* ew = (const float*)d_in[2];
    const float* Wp0 = (const float*)d_in[4];
    const float* bp0 = (const float*)d_in[5];
    const float* Wn0 = (const float*)d_in[6];
    const float* bn0 = (const float*)d_in[7];
    const float* Wp1 = (const float*)d_in[8];
    const float* bp1 = (const float*)d_in[9];
    const float* Wn1 = (const float*)d_in[10];
    const float* bn1 = (const float*)d_in[11];
    const float* Wp2 = (const float*)d_in[12];
    const float* bp2 = (const float*)d_in[13];
    const float* Wn2 = (const float*)d_in[14];
    const float* bn2 = (const float*)d_in[15];
    const float* Wr  = (const float*)d_in[16];
    const float* br  = (const float*)d_in[17];
    const float* Wl  = (const float*)d_in[18];
    const float* bl  = (const float*)d_in[19];
    const int E = in_sizes[1] / 2;   // 409600

    // ---- workspace layout (bytes) ----
    char* ws = (char*)d_ws;
    float*    partial = (float*)(ws + 0);             // 64*64*256 fp32 = 4194304
    uint_t*   bh      = (uint_t*)(ws + 4194304);      // 128*12800*4 -> 10747904
    int*      counts  = (int*)(ws + 10747904);        // -> 10799104
    int*      cnt_p   = (int*)(ws + 10799104);        // -> 10850304
    uint2*    obnd    = (uint2*)(ws + 10850304);      // -> 10952768
    uint2*    es      = (uint2*)(ws + 10952768);      // E*8 -> 14229568
    ushort_t* Ap      = (ushort_t*)(ws + 14229568);   // 12800*512 bf16 -> 27336768
    ushort_t* An      = (ushort_t*)(ws + 27336768);   // -> 40443968
    ushort_t* hA      = (ushort_t*)(ws + 40443968);   // 12800*256 bf16 -> 46997568
    ushort_t* hB      = (ushort_t*)(ws + 46997568);   // -> 53551168
    ushort_t* wcast   = (ushort_t*)(ws + 53551168);   // 6*65536 bf16 -> 54337600
    ushort_t* xb      = (ushort_t*)(ws + 54337600);   // 12800*200 bf16 -> 59457600

    ushort_t* w0p = wcast + 0 * 65536;
    ushort_t* w0n = wcast + 1 * 65536;
    ushort_t* w1p = wcast + 2 * 65536;
    ushort_t* w1n = wcast + 3 * 65536;
    ushort_t* w2p = wcast + 4 * 65536;
    ushort_t* w2n = wcast + 5 * 65536;

    // CSR build
    hipLaunchKernelGGL(bhist_kernel, dim3(HBLK), dim3(1024), 0, stream, ei, ew, bh, E);
    hipLaunchKernelGGL(colpref_kernel, dim3((N_NODES + 255) / 256), dim3(256), 0, stream,
                       bh, counts, cnt_p);
    hipLaunchKernelGGL(scan_kernel, dim3(1), dim3(1024), 0, stream, counts, cnt_p, obnd, N_NODES);
    // scatter + all casts in one launch
    hipLaunchKernelGGL(scat_prep_kernel, dim3(1137), dim3(1024), 0, stream,
                       ei, ew, bh, obnd, es, E,
                       Wp0, Wn0, Wp1, Wn1, Wp2, Wn2, x, wcast, xb);

    // layer 0: in = xb (bf16, D=200), KSTEPS = 13 (covers padded 416)
    hipLaunchKernelGGL((agg_kernel<FEAT>), dim3(N_NODES / 4), dim3(256), 0, stream,
                       xb, obnd, es, Ap, An);
    hipLaunchKernelGGL((conv_mfma<13, true>), dim3(N_NODES / 64, 2), dim3(256), 0, stream,
                       Ap, An, w0p, w0n, bp0, bn0, hA);
    // layer 1
    hipLaunchKernelGGL((agg_kernel<HID>), dim3(N_NODES / 4), dim3(256), 0, stream,
                       hA, obnd, es, Ap, An);
    hipLaunchKernelGGL((conv_mfma<16, true>), dim3(N_NODES / 64, 2), dim3(256), 0, stream,
                       Ap, An, w1p, w1n, bp1, bn1, hB);
    // layer 2
    hipLaunchKernelGGL((agg_kernel<HID>), dim3(N_NODES / 4), dim3(256), 0, stream,
                       hB, obnd, es, Ap, An);
    hipLaunchKernelGGL((conv_mfma<16, false>), dim3(N_NODES / 64, 2), dim3(256), 0, stream,
                       Ap, An, w2p, w2n, bp2, bn2, hA);

    // readout + final
    hipLaunchKernelGGL(readout_mfma, dim3(4, 64), dim3(256), 0, stream, hA, Wr, partial);
    hipLaunchKernelGGL(final_kernel, dim3(NUM_GRAPHS), dim3(256), 0, stream,
                       partial, br, Wl, bl, (float*)d_out);
}

// Round 12
// 311.323 us; speedup vs baseline: 1.0513x; 1.0513x over previous
//
#include <hip/hip_runtime.h>

// ---------------- problem constants ----------------
#define NUM_GRAPHS 64
#define NODE_SZ    200
#define FEAT       200
#define HID        256
#define HALF       128
#define N_NODES    (NUM_GRAPHS * NODE_SZ)   // 12800
#define KREAD      (NODE_SZ * HID)          // 51200
#define KSTRIDE    512                      // padded K for conv inputs/weights
#define HBLK       128                      // histogram/scatter blocks

typedef unsigned short ushort_t;
typedef unsigned int uint_t;
typedef __attribute__((ext_vector_type(8))) short bf16x8;
typedef __attribute__((ext_vector_type(4))) float f32x4;

#define GAS(p) ((const __attribute__((address_space(1))) void*)(p))
#define LAS(p) ((__attribute__((address_space(3))) void*)(p))

__device__ __forceinline__ float bf2f(ushort_t u) {
    union { unsigned int i; float f; } v; v.i = ((unsigned int)u) << 16; return v.f;
}
__device__ __forceinline__ ushort_t f2bf(float f) {
    union { float f; unsigned int i; } v; v.f = f;
    unsigned int x = v.i;
    unsigned int r = (x + 0x7fffu + ((x >> 16) & 1u)) >> 16;  // RNE
    return (ushort_t)r;
}

// ---------------- CSR build (no global atomics) ----------------
__global__ __launch_bounds__(1024) void bhist_kernel(const int* __restrict__ ei,
                                                     const float* __restrict__ ew,
                                                     uint_t* __restrict__ bh, int E) {
    __shared__ uint_t h[N_NODES];
    for (int i = threadIdx.x; i < N_NODES; i += 1024) h[i] = 0;
    __syncthreads();
    int b = blockIdx.x;
    int epb = (E + HBLK - 1) / HBLK;
    int e0 = b * epb, e1 = min(e0 + epb, E);
    for (int e = e0 + threadIdx.x; e < e1; e += 1024) {
        int dst = ei[E + e];
        float w = ew[e];
        if (w > 0.0f)      atomicAdd(&h[dst], 1u);
        else if (w < 0.0f) atomicAdd(&h[dst], 0x10000u);
    }
    __syncthreads();
    uint_t* out = bh + (size_t)b * N_NODES;
    for (int i = threadIdx.x * 4; i < N_NODES; i += 4096)
        *(uint4*)&out[i] = *(const uint4*)&h[i];
}

// Column prefix over the block-histograms; ILP-8 batched loads (latency hiding).
__global__ void colpref_kernel(uint_t* __restrict__ bh, int* __restrict__ counts,
                               int* __restrict__ cnt_p) {
    int n = blockIdx.x * 256 + threadIdx.x;
    if (n >= N_NODES) return;
    uint_t seq = 0;
#pragma unroll 1
    for (int b = 0; b < HBLK; b += 8) {
        uint_t v[8];
#pragma unroll
        for (int j = 0; j < 8; ++j) v[j] = bh[(size_t)(b + j) * N_NODES + n];
#pragma unroll
        for (int j = 0; j < 8; ++j) {
            bh[(size_t)(b + j) * N_NODES + n] = seq;
            seq += v[j];
        }
    }
    counts[n] = (int)((seq & 0xffffu) + (seq >> 16));
    cnt_p[n]  = (int)(seq & 0xffffu);
}

__global__ __launch_bounds__(1024) void scan_kernel(const int* __restrict__ counts,
                                                    const int* __restrict__ cnt_p,
                                                    uint2* __restrict__ obnd, int n) {
    const int PER = 13;
    int t = threadIdx.x;
    int start = t * PER;
    int local[PER];
    int sum = 0;
#pragma unroll
    for (int i = 0; i < PER; ++i) {
        int idx = start + i;
        int v = (idx < n) ? counts[idx] : 0;
        local[i] = sum;
        sum += v;
    }
    int lane = t & 63, wid = t >> 6;
    int inc = sum;
#pragma unroll
    for (int d = 1; d < 64; d <<= 1) {
        int up = __shfl_up(inc, d);
        if (lane >= d) inc += up;
    }
    __shared__ int wsum[16], woff[16];
    if (lane == 63) wsum[wid] = inc;
    __syncthreads();
    if (t < 16) {
        int acc = 0;
        for (int j = 0; j < 16; ++j) if (j < t) acc += wsum[j];
        woff[t] = acc;
    }
    __syncthreads();
    int base = woff[wid] + (inc - sum);
#pragma unroll
    for (int i = 0; i < PER; ++i) {
        int idx = start + i;
        if (idx < n) {
            uint_t off = (uint_t)(base + local[i]);
            obnd[idx] = make_uint2(off, off + (uint_t)cnt_p[idx]);
        }
    }
    if (t == 1023) {
        uint_t tot = (uint_t)(base + sum);
        obnd[n] = make_uint2(tot, tot);
    }
}

// ---------------- scatter + all casts, one launch ----------------
// blocks [0,128): scatter; [128,512): weight castpad; [512,1137): x cast.
__global__ __launch_bounds__(1024) void scat_prep_kernel(
        const int* __restrict__ ei, const float* __restrict__ ew,
        const uint_t* __restrict__ bh, const uint2* __restrict__ obnd,
        uint2* __restrict__ es, int E,
        const float* __restrict__ W0p, const float* __restrict__ W0n,
        const float* __restrict__ W1p, const float* __restrict__ W1n,
        const float* __restrict__ W2p, const float* __restrict__ W2n,
        const float* __restrict__ x,
        ushort_t* __restrict__ wcast, ushort_t* __restrict__ xb) {
    __shared__ uint_t cur[N_NODES];
    int bx = blockIdx.x;
    if (bx < HBLK) {
        const uint_t* pref = bh + (size_t)bx * N_NODES;
        for (int i = threadIdx.x * 4; i < N_NODES; i += 4096)
            *(uint4*)&cur[i] = *(const uint4*)&pref[i];
        __syncthreads();
        int epb = (E + HBLK - 1) / HBLK;
        int e0 = bx * epb, e1 = min(e0 + epb, E);
        for (int e = e0 + threadIdx.x; e < e1; e += 1024) {
            int src = ei[e];
            int dst = ei[E + e];
            float w = ew[e];
            if (w > 0.0f) {
                uint_t old = atomicAdd(&cur[dst], 1u);
                uint_t pos = obnd[dst].x + (old & 0xffffu);
                es[pos] = make_uint2((uint_t)src, __float_as_uint(w));
            } else if (w < 0.0f) {
                uint_t old = atomicAdd(&cur[dst], 0x10000u);
                uint_t pos = obnd[dst].y + (old >> 16);
                es[pos] = make_uint2((uint_t)src, __float_as_uint(-w));
            }
        }
    } else if (bx < 512) {
        int idx = (bx - 128) * 1024 + threadIdx.x;      // < 6*65536
        int task = idx >> 16;
        int within = idx & 65535;
        const float* W = (task == 0) ? W0p : (task == 1) ? W0n : (task == 2) ? W1p
                       : (task == 3) ? W1n : (task == 4) ? W2p : W2n;
        int K2 = (task < 2) ? 400 : 512;
        int row = within >> 9;
        int col = within & (KSTRIDE - 1);
        wcast[task * 65536 + within] = (col < K2) ? f2bf(W[(size_t)row * K2 + col]) : (ushort_t)0;
    } else {
        int i = ((bx - 512) * 1024 + threadIdx.x) * 4;
        if (i < N_NODES * FEAT) {
            float4 v = *(const float4*)&x[i];
            ushort4 o;
            o.x = f2bf(v.x); o.y = f2bf(v.y); o.z = f2bf(v.z); o.w = f2bf(v.w);
            *(ushort4*)&xb[i] = o;
        }
    }
}

// ---------------- signed aggregation: 4 waves/block, one node per wave, ILP-8 (r10) ----------------
template <int D>
__global__ __launch_bounds__(256) void agg_kernel(
        const ushort_t* __restrict__ hb,
        const uint2* __restrict__ obnd,
        const uint2* __restrict__ es,
        ushort_t* __restrict__ Ap, ushort_t* __restrict__ An) {
    constexpr int ACT = D / 4;
    int lane = threadIdx.x & 63;
    int wv   = threadIdx.x >> 6;
    int n = blockIdx.x * 4 + wv;
    int c0 = min(lane, ACT - 1) * 4;
    uint2 ob = obnd[n];
    uint_t off = ob.x, mid = ob.y, end = obnd[n + 1].x;

    float ap[4] = {0.f, 0.f, 0.f, 0.f};
    float an[4] = {0.f, 0.f, 0.f, 0.f};

#pragma unroll 1
    for (int phase = 0; phase < 2; ++phase) {
        uint_t lo = phase ? mid : off;
        uint_t hi = phase ? end : mid;
        float* acc = phase ? an : ap;
#pragma unroll 1
        for (uint_t base = lo; base < hi; base += 64) {
            int cnt = (int)min(64u, hi - base);
            uint2 rec = es[base + (uint_t)min(lane, cnt - 1)];
            int i = 0;
#pragma unroll 1
            for (; i + 8 <= cnt; i += 8) {
                int s[8]; float w[8]; uint2 p[8];
#pragma unroll
                for (int j = 0; j < 8; ++j) {
                    s[j] = __shfl((int)rec.x, i + j);
                    w[j] = __uint_as_float((uint_t)__shfl((int)rec.y, i + j));
                }
#pragma unroll
                for (int j = 0; j < 8; ++j) p[j] = *(const uint2*)&hb[(size_t)s[j] * D + c0];
#pragma unroll
                for (int j = 0; j < 8; ++j) {
                    const ushort_t* q = (const ushort_t*)&p[j];
#pragma unroll
                    for (int c = 0; c < 4; ++c) acc[c] = fmaf(w[j], bf2f(q[c]), acc[c]);
                }
            }
#pragma unroll 1
            for (; i < cnt; ++i) {
                int s = __shfl((int)rec.x, i);
                float w = __uint_as_float((uint_t)__shfl((int)rec.y, i));
                uint2 pk = *(const uint2*)&hb[(size_t)s * D + c0];
                const ushort_t* q = (const ushort_t*)&pk;
#pragma unroll
                for (int c = 0; c < 4; ++c) acc[c] = fmaf(w, bf2f(q[c]), acc[c]);
            }
        }
    }

    size_t rb = (size_t)n * KSTRIDE;
    if (lane < ACT) {
        float dp = fmaxf((float)(mid - off), 1.0f);
        float dn = fmaxf((float)(end - mid), 1.0f);
        uint2 pk = *(const uint2*)&hb[(size_t)n * D + c0];
        const ushort_t* p = (const ushort_t*)&pk;
        ushort4 os = {p[0], p[1], p[2], p[3]};
        ushort4 op, on;
        op.x = f2bf(ap[0] / dp); op.y = f2bf(ap[1] / dp);
        op.z = f2bf(ap[2] / dp); op.w = f2bf(ap[3] / dp);
        on.x = f2bf(an[0] / dn); on.y = f2bf(an[1] / dn);
        on.z = f2bf(an[2] / dn); on.w = f2bf(an[3] / dn);
        *(ushort4*)&Ap[rb + c0] = op;
        *(ushort4*)&An[rb + c0] = on;
        *(ushort4*)&Ap[rb + D + c0] = os;
        *(ushort4*)&An[rb + D + c0] = os;
    }
    if (D == 200 && lane >= 50 && lane < 54) {   // zero pad cols 400..415
        ushort4 z = {0, 0, 0, 0};
        *(ushort4*)&Ap[rb + 400 + (lane - 50) * 4] = z;
        *(ushort4*)&An[rb + 400 + (lane - 50) * 4] = z;
    }
}

// ---------------- conv linear via MFMA: M-tile 32, grid (400,2) for occupancy ----------------
// Wave wv owns N-cols [wv*32, +32) x all 32 M-rows (2 M-frags x 2 N-frags = 4 MFMAs/K-step).
template <int KSTEPS, bool LEAKY>
__global__ __launch_bounds__(256) void conv_mfma(
        const ushort_t* __restrict__ Ap, const ushort_t* __restrict__ An,
        const ushort_t* __restrict__ Wpb, const ushort_t* __restrict__ Wnb,
        const float* __restrict__ bp, const float* __restrict__ bn,
        ushort_t* __restrict__ hout) {
    __shared__ __align__(16) ushort_t As[2][32 * 32];    // 2 x 2 KB
    __shared__ __align__(16) ushort_t Bs[2][128 * 32];   // 2 x 8 KB
    int mBase = blockIdx.x * 32;
    bool neg = (blockIdx.y != 0);
    const ushort_t* A    = neg ? An : Ap;
    const ushort_t* W    = neg ? Wnb : Wpb;
    const float*    bias = neg ? bn : bp;
    int tid  = threadIdx.x;
    int lane = tid & 63;
    int wv   = tid >> 6;
    int r    = lane & 15;
    int quad = lane >> 4;

    int rowA = tid >> 2, colA = (tid & 3) * 8;           // A valid for tid < 128 (rows 0..31)
    const ushort_t* gA  = A + (size_t)(mBase + (rowA & 31)) * KSTRIDE + colA;
    const ushort_t* gB0 = W + (size_t)rowA * KSTRIDE + colA;
    const ushort_t* gB1 = W + (size_t)(rowA + 64) * KSTRIDE + colA;

    f32x4 acc00 = {0.f,0.f,0.f,0.f}, acc01 = {0.f,0.f,0.f,0.f};
    f32x4 acc10 = {0.f,0.f,0.f,0.f}, acc11 = {0.f,0.f,0.f,0.f};

    if (tid < 128)
        __builtin_amdgcn_global_load_lds(GAS(gA), LAS(&As[0][wv * 512]), 16, 0, 0);
    __builtin_amdgcn_global_load_lds(GAS(gB0), LAS(&Bs[0][wv * 512]), 16, 0, 0);
    __builtin_amdgcn_global_load_lds(GAS(gB1), LAS(&Bs[0][2048 + wv * 512]), 16, 0, 0);

    for (int kt = 0; kt < KSTEPS; ++kt) {
        int cur = kt & 1;
        __syncthreads();
        if (kt + 1 < KSTEPS) {
            int kB = (kt + 1) * 32;
            if (tid < 128)
                __builtin_amdgcn_global_load_lds(GAS(gA + kB), LAS(&As[cur ^ 1][wv * 512]), 16, 0, 0);
            __builtin_amdgcn_global_load_lds(GAS(gB0 + kB), LAS(&Bs[cur ^ 1][wv * 512]), 16, 0, 0);
            __builtin_amdgcn_global_load_lds(GAS(gB1 + kB), LAS(&Bs[cur ^ 1][2048 + wv * 512]), 16, 0, 0);
        }
        bf16x8 a0 = *(const bf16x8*)&As[cur][r * 32 + quad * 8];
        bf16x8 a1 = *(const bf16x8*)&As[cur][(16 + r) * 32 + quad * 8];
        bf16x8 b0 = *(const bf16x8*)&Bs[cur][(wv * 32 + r) * 32 + quad * 8];
        bf16x8 b1 = *(const bf16x8*)&Bs[cur][(wv * 32 + 16 + r) * 32 + quad * 8];
        acc00 = __builtin_amdgcn_mfma_f32_16x16x32_bf16(a0, b0, acc00, 0, 0, 0);
        acc01 = __builtin_amdgcn_mfma_f32_16x16x32_bf16(a0, b1, acc01, 0, 0, 0);
        acc10 = __builtin_amdgcn_mfma_f32_16x16x32_bf16(a1, b0, acc10, 0, 0, 0);
        acc11 = __builtin_amdgcn_mfma_f32_16x16x32_bf16(a1, b1, acc11, 0, 0, 0);
    }
    int colOff = neg ? HALF : 0;
#pragma unroll
    for (int jn = 0; jn < 2; ++jn) {
        int cl = wv * 32 + jn * 16 + r;                  // within-branch col 0..127
        float bv = bias[cl];
        f32x4 am0 = jn ? acc01 : acc00;
        f32x4 am1 = jn ? acc11 : acc10;
#pragma unroll
        for (int reg = 0; reg < 4; ++reg) {
            int m0 = mBase + quad * 4 + reg;
            int m1 = m0 + 16;
            float v0 = am0[reg] + bv;
            float v1 = am1[reg] + bv;
            if (LEAKY) {
                v0 = (v0 > 0.0f) ? v0 : 0.01f * v0;
                v1 = (v1 > 0.0f) ? v1 : 0.01f * v1;
            }
            hout[(size_t)m0 * HID + colOff + cl] = f2bf(v0);
            hout[(size_t)m1 * HID + colOff + cl] = f2bf(v1);
        }
    }
}

// ---------------- readout via MFMA, split-K partials (no atomics) ----------------
__global__ __launch_bounds__(256) void readout_mfma(
        const ushort_t* __restrict__ h, const float* __restrict__ Wr,
        float* __restrict__ partial) {
    __shared__ __align__(16) ushort_t As[64 * 32];
    __shared__ __align__(16) ushort_t Bs[64 * 32];
    int nBase  = blockIdx.x * 64;
    int kStart = blockIdx.y * 800;
    int tid  = threadIdx.x;
    int lane = tid & 63;
    int wv   = tid >> 6;
    int r    = lane & 15;
    int quad = lane >> 4;

    f32x4 acc[4];
#pragma unroll
    for (int j = 0; j < 4; ++j) acc[j] = (f32x4){0.f, 0.f, 0.f, 0.f};

    for (int kt = 0; kt < 25; ++kt) {
        int kBase = kStart + kt * 32;
        int lin = tid * 8;
        int row = lin >> 5, col = lin & 31;
        *(uint4*)&As[lin] = *(const uint4*)&h[(size_t)row * KREAD + kBase + col];
        {
            const float* wp = &Wr[(size_t)(nBase + row) * KREAD + kBase + col];
            float4 f0 = *(const float4*)&wp[0];
            float4 f1 = *(const float4*)&wp[4];
            ushort4 b0, b1;
            b0.x = f2bf(f0.x); b0.y = f2bf(f0.y); b0.z = f2bf(f0.z); b0.w = f2bf(f0.w);
            b1.x = f2bf(f1.x); b1.y = f2bf(f1.y); b1.z = f2bf(f1.z); b1.w = f2bf(f1.w);
            *(ushort4*)&Bs[lin]     = b0;
            *(ushort4*)&Bs[lin + 4] = b1;
        }
        __syncthreads();
        bf16x8 a = *(const bf16x8*)&As[(wv * 16 + r) * 32 + quad * 8];
#pragma unroll
        for (int j = 0; j < 4; ++j) {
            bf16x8 b = *(const bf16x8*)&Bs[(j * 16 + r) * 32 + quad * 8];
            acc[j] = __builtin_amdgcn_mfma_f32_16x16x32_bf16(a, b, acc[j], 0, 0, 0);
        }
        __syncthreads();
    }
    float* out = partial + (size_t)blockIdx.y * (64 * HID);
#pragma unroll
    for (int j = 0; j < 4; ++j) {
        int c = nBase + j * 16 + r;
#pragma unroll
        for (int reg = 0; reg < 4; ++reg) {
            int g = wv * 16 + quad * 4 + reg;
            out[g * HID + c] = acc[j][reg];
        }
    }
}

// ---------------- final: fold 64 partials, dot with Wl ----------------
__global__ void final_kernel(const float* __restrict__ partial, const float* __restrict__ br,
                             const float* __restrict__ Wl, const float* __restrict__ bl,
                             float* __restrict__ out) {
    int g = blockIdx.x;
    int c = threadIdx.x;   // 256
    float s = 0.0f;
#pragma unroll 4
    for (int k = 0; k < 64; ++k) s += partial[(size_t)k * (64 * HID) + g * HID + c];
    float v = (s + br[c]) * Wl[c];
#pragma unroll
    for (int d = 32; d > 0; d >>= 1) v += __shfl_down(v, d);
    __shared__ float sh[4];
    if ((c & 63) == 0) sh[c >> 6] = v;
    __syncthreads();
    if (c == 0) out[g] = sh[0] + sh[1] + sh[2] + sh[3] + bl[0];
}

// ---------------- launch ----------------
extern "C" void kernel_launch(void* const* d_in, const int* in_sizes, int n_in,
                              void* d_out, int out_size, void* d_ws, size_t ws_size,
                              hipStream_t stream) {
    const float* x  = (const float*)d_in[0];
    const int*   ei = (const int*)d_in[1];
    const float* ew = (const float*)d_in[2];
    const float* Wp0 = (const float*)d_in[4];
    const float* bp0 = (const float*)d_in[5];
    const float* Wn0 = (const float*)d_in[6];
    const float* bn0 = (const float*)d_in[7];
    const float* Wp1 = (const float*)d_in[8];
    const float* bp1 = (const float*)d_in[9];
    const float* Wn1 = (const float*)d_in[10];
    const float* bn1 = (const float*)d_in[11];
    const float* Wp2 = (const float*)d_in[12];
    const float* bp2 = (const float*)d_in[13];
    const float* Wn2 = (const float*)d_in[14];
    const float* bn2 = (const float*)d_in[15];
    const float* Wr  = (const float*)d_in[16];
    const float* br  = (const float*)d_in[17];
    const float* Wl  = (const float*)d_in[18];
    const float* bl  = (const float*)d_in[19];
    const int E = in_sizes[1] / 2;   // 409600

    // ---- workspace layout (bytes) ----
    char* ws = (char*)d_ws;
    float*    partial = (float*)(ws + 0);             // 64*64*256 fp32 = 4194304
    uint_t*   bh      = (uint_t*)(ws + 4194304);      // 128*12800*4 -> 10747904
    int*      counts  = (int*)(ws + 10747904);        // -> 10799104
    int*      cnt_p   = (int*)(ws + 10799104);        // -> 10850304
    uint2*    obnd    = (uint2*)(ws + 10850304);      // -> 10952768
    uint2*    es      = (uint2*)(ws + 10952768);      // E*8 -> 14229568
    ushort_t* Ap      = (ushort_t*)(ws + 14229568);   // 12800*512 bf16 -> 27336768
    ushort_t* An      = (ushort_t*)(ws + 27336768);   // -> 40443968
    ushort_t* hA      = (ushort_t*)(ws + 40443968);   // 12800*256 bf16 -> 46997568
    ushort_t* hB      = (ushort_t*)(ws + 46997568);   // -> 53551168
    ushort_t* wcast   = (ushort_t*)(ws + 53551168);   // 6*65536 bf16 -> 54337600
    ushort_t* xb      = (ushort_t*)(ws + 54337600);   // 12800*200 bf16 -> 59457600

    ushort_t* w0p = wcast + 0 * 65536;
    ushort_t* w0n = wcast + 1 * 65536;
    ushort_t* w1p = wcast + 2 * 65536;
    ushort_t* w1n = wcast + 3 * 65536;
    ushort_t* w2p = wcast + 4 * 65536;
    ushort_t* w2n = wcast + 5 * 65536;

    // CSR build
    hipLaunchKernelGGL(bhist_kernel, dim3(HBLK), dim3(1024), 0, stream, ei, ew, bh, E);
    hipLaunchKernelGGL(colpref_kernel, dim3((N_NODES + 255) / 256), dim3(256), 0, stream,
                       bh, counts, cnt_p);
    hipLaunchKernelGGL(scan_kernel, dim3(1), dim3(1024), 0, stream, counts, cnt_p, obnd, N_NODES);
    // scatter + all casts in one launch
    hipLaunchKernelGGL(scat_prep_kernel, dim3(1137), dim3(1024), 0, stream,
                       ei, ew, bh, obnd, es, E,
                       Wp0, Wn0, Wp1, Wn1, Wp2, Wn2, x, wcast, xb);

    // layer 0: in = xb (bf16, D=200), KSTEPS = 13 (covers padded 416)
    hipLaunchKernelGGL((agg_kernel<FEAT>), dim3(N_NODES / 4), dim3(256), 0, stream,
                       xb, obnd, es, Ap, An);
    hipLaunchKernelGGL((conv_mfma<13, true>), dim3(N_NODES / 32, 2), dim3(256), 0, stream,
                       Ap, An, w0p, w0n, bp0, bn0, hA);
    // layer 1
    hipLaunchKernelGGL((agg_kernel<HID>), dim3(N_NODES / 4), dim3(256), 0, stream,
                       hA, obnd, es, Ap, An);
    hipLaunchKernelGGL((conv_mfma<16, true>), dim3(N_NODES / 32, 2), dim3(256), 0, stream,
                       Ap, An, w1p, w1n, bp1, bn1, hB);
    // layer 2
    hipLaunchKernelGGL((agg_kernel<HID>), dim3(N_NODES / 4), dim3(256), 0, stream,
                       hB, obnd, es, Ap, An);
    hipLaunchKernelGGL((conv_mfma<16, false>), dim3(N_NODES / 32, 2), dim3(256), 0, stream,
                       Ap, An, w2p, w2n, bp2, bn2, hA);

    // readout + final
    hipLaunchKernelGGL(readout_mfma, dim3(4, 64), dim3(256), 0, stream, hA, Wr, partial);
    hipLaunchKernelGGL(final_kernel, dim3(NUM_GRAPHS), dim3(256), 0, stream,
                       partial, br, Wl, bl, (float*)d_out);
}